// Round 6
// baseline (12559.167 us; speedup 1.0000x reference)
//
#include <hip/hip_runtime.h>
#include <math.h>

#define Bn 4
#define Cn 1024
#define RCn 64
#define Tn 16
#define Hn 28
#define Wn 28
#define HWn 784
#define THWn 12544
#define TC 4  // t-chunk for Gn/Gp buffers

__device__ __forceinline__ float sigm5(float x) {
  return 1.0f / (1.0f + __expf(-x)) - 0.5f;
}

__device__ __forceinline__ void fma16(const float4 a, const float4 b, float (&acc)[4][4]) {
  acc[0][0] = fmaf(a.x, b.x, acc[0][0]);
  acc[0][1] = fmaf(a.x, b.y, acc[0][1]);
  acc[0][2] = fmaf(a.x, b.z, acc[0][2]);
  acc[0][3] = fmaf(a.x, b.w, acc[0][3]);
  acc[1][0] = fmaf(a.y, b.x, acc[1][0]);
  acc[1][1] = fmaf(a.y, b.y, acc[1][1]);
  acc[1][2] = fmaf(a.y, b.z, acc[1][2]);
  acc[1][3] = fmaf(a.y, b.w, acc[1][3]);
  acc[2][0] = fmaf(a.z, b.x, acc[2][0]);
  acc[2][1] = fmaf(a.z, b.y, acc[2][1]);
  acc[2][2] = fmaf(a.z, b.z, acc[2][2]);
  acc[2][3] = fmaf(a.z, b.w, acc[2][3]);
  acc[3][0] = fmaf(a.w, b.x, acc[3][0]);
  acc[3][1] = fmaf(a.w, b.y, acc[3][1]);
  acc[3][2] = fmaf(a.w, b.z, acc[3][2]);
  acc[3][3] = fmaf(a.w, b.w, acc[3][3]);
}

// C[m,n] = sum_k A[m,k]*B[k,n]; A row-major MxK (shared over z),
// B row-major KxN (+ bz*sB), C row-major MxN (+ bz*sC).
// All calls: N%64==0, K%32==0, M covered by grid.y*64 (no bounds checks).
__global__ __launch_bounds__(256) void gemm_nn(const float* __restrict__ A,
                                               const float* __restrict__ B,
                                               float* __restrict__ C,
                                               int M, int N, int K,
                                               long sB, long sC) {
  __shared__ __align__(16) float As[32][68];
  __shared__ __align__(16) float Bs[32][68];
  const int tid = threadIdx.x;
  const int i0 = blockIdx.y * 64, j0 = blockIdx.x * 64;
  const float* Bp = B + (long)blockIdx.z * sB;
  float* Cp = C + (long)blockIdx.z * sC;
  const int tx = tid & 15, ty = tid >> 4;
  const int lm = tid >> 2, lk = (tid & 3) * 4;
  const int bkk = tid >> 4, bn = (tid & 15) * 4;
  float acc[4][4] = {};
  for (int k0 = 0; k0 < K; k0 += 32) {
#pragma unroll
    for (int h = 0; h < 2; ++h) {
      float4 av = *(const float4*)&A[(long)(i0 + lm) * K + (k0 + lk + h * 16)];
      As[lk + h * 16 + 0][lm] = av.x;
      As[lk + h * 16 + 1][lm] = av.y;
      As[lk + h * 16 + 2][lm] = av.z;
      As[lk + h * 16 + 3][lm] = av.w;
      *(float4*)&Bs[bkk + h * 16][bn] =
          *(const float4*)&Bp[(long)(k0 + bkk + h * 16) * N + (j0 + bn)];
    }
    __syncthreads();
#pragma unroll
    for (int kk = 0; kk < 32; ++kk) {
      float4 a = *(const float4*)&As[kk][ty * 4];
      float4 b = *(const float4*)&Bs[kk][tx * 4];
      fma16(a, b, acc);
    }
    __syncthreads();
  }
#pragma unroll
  for (int i = 0; i < 4; ++i) {
    float4 v = make_float4(acc[i][0], acc[i][1], acc[i][2], acc[i][3]);
    *(float4*)&Cp[(long)(i0 + ty * 4 + i) * N + (j0 + tx * 4)] = v;
  }
}

// Affinities for one b, t-chunk [t0, t0+TC):
// S[hw,sd] = sum_c X[c,t,hw]*X2[c,ts,sd]; store sigmoid(S)-0.5 into G[dt].
// z = pair*TC + dt. pair 0 -> next (Gn), pair 1 -> prev (Gp).
__global__ __launch_bounds__(256) void aff_tn(const float* __restrict__ Xb,
                                              const float* __restrict__ X2,
                                              float* __restrict__ Gn,
                                              float* __restrict__ Gp,
                                              int t0) {
  const int z = blockIdx.z;
  const int dt = z & (TC - 1);
  const int pair = z / TC;
  const int t = t0 + dt;
  const int ts = pair ? (t > 0 ? t - 1 : 0) : (t < Tn - 1 ? t + 1 : Tn - 1);
  const float* Ap = Xb + (long)t * HWn;   // + k*THWn + m
  const float* Bp = X2 + (long)ts * HWn;  // + k*THWn + n
  float* G = (pair ? Gp : Gn) + (long)dt * HWn * HWn;
  const int i0 = blockIdx.y * 64, j0 = blockIdx.x * 64;
  __shared__ __align__(16) float As[32][68];
  __shared__ __align__(16) float Bs[32][68];
  const int tid = threadIdx.x;
  const int tx = tid & 15, ty = tid >> 4;
  const int lkk = tid >> 4, lm4 = (tid & 15) * 4;
  const bool ain = (i0 + lm4) < HWn;
  const bool bin = (j0 + lm4) < HWn;
  float acc[4][4] = {};
  for (int k0 = 0; k0 < Cn; k0 += 32) {
#pragma unroll
    for (int h = 0; h < 2; ++h) {
      const int kk = lkk + h * 16;
      float4 av = ain ? *(const float4*)&Ap[(long)(k0 + kk) * THWn + (i0 + lm4)]
                      : make_float4(0.f, 0.f, 0.f, 0.f);
      *(float4*)&As[kk][lm4] = av;
      float4 bv = bin ? *(const float4*)&Bp[(long)(k0 + kk) * THWn + (j0 + lm4)]
                      : make_float4(0.f, 0.f, 0.f, 0.f);
      *(float4*)&Bs[kk][lm4] = bv;
    }
    __syncthreads();
#pragma unroll
    for (int kk = 0; kk < 32; ++kk) {
      float4 a = *(const float4*)&As[kk][ty * 4];
      float4 b = *(const float4*)&Bs[kk][tx * 4];
      fma16(a, b, acc);
    }
    __syncthreads();
  }
  const int n = j0 + tx * 4;
  if (n < HWn) {
#pragma unroll
    for (int i = 0; i < 4; ++i) {
      const int m = i0 + ty * 4 + i;
      if (m < HWn) {
        float4 v = make_float4(sigm5(acc[i][0]), sigm5(acc[i][1]),
                               sigm5(acc[i][2]), sigm5(acc[i][3]));
        *(float4*)&G[(long)m * HWn + n] = v;
      }
    }
  }
}

// Features + gate epilogue for one (b, t), t = t0 + blockIdx.z:
// F[c,hw] = sum_sd X2n[c,sd]*Gn[hw,sd]*w2[0] + X2p[c,sd]*Gp[hw,sd]*w2[1]
// out[c,hw] = F * (sigmoid(sum_r w_back[c,r]*agg[r,t,hw]) - 0.5)
__global__ __launch_bounds__(256) void feat_nt(const float* __restrict__ X2,
                                               const float* __restrict__ Gn,
                                               const float* __restrict__ Gp,
                                               const float* __restrict__ aggb,
                                               const float* __restrict__ w_back,
                                               const float* __restrict__ w2p,
                                               float* __restrict__ outb,
                                               int t0) {
  const int dt = blockIdx.z;
  const int t = t0 + dt;
  const int tnext = (t < Tn - 1) ? t + 1 : Tn - 1;
  const int tprev = (t > 0) ? t - 1 : 0;
  const int i0 = blockIdx.y * 64, j0 = blockIdx.x * 64;
  __shared__ __align__(16) float As[32][68];
  __shared__ __align__(16) float Bs[32][68];
  __shared__ __align__(16) float Wb[64][68];
  __shared__ __align__(16) float Ag[64][68];
  const int tid = threadIdx.x;
  const int tx = tid & 15, ty = tid >> 4;
  const int lm = tid >> 2, lk4 = (tid & 3) * 4;
  float acc[4][4] = {};
  const bool nin = (j0 + lm) < HWn;
  for (int pair = 0; pair < 2; ++pair) {
    const int tt = pair ? tprev : tnext;
    const float* G = (pair ? Gp : Gn) + (long)dt * HWn * HWn;
    const float scale = w2p[pair];
    const float* Ab = X2 + (long)tt * HWn;  // + m*THWn + k
    for (int k0 = 0; k0 < HWn; k0 += 32) {
#pragma unroll
      for (int h = 0; h < 2; ++h) {
        const int k = k0 + lk4 + h * 16;
        const bool kin = k < HWn;
        float4 av = kin ? *(const float4*)&Ab[(long)(i0 + lm) * THWn + k]
                        : make_float4(0.f, 0.f, 0.f, 0.f);
        As[lk4 + h * 16 + 0][lm] = av.x;
        As[lk4 + h * 16 + 1][lm] = av.y;
        As[lk4 + h * 16 + 2][lm] = av.z;
        As[lk4 + h * 16 + 3][lm] = av.w;
        float4 bv = (kin && nin)
                        ? *(const float4*)&G[(long)(j0 + lm) * HWn + k]
                        : make_float4(0.f, 0.f, 0.f, 0.f);
        Bs[lk4 + h * 16 + 0][lm] = bv.x * scale;
        Bs[lk4 + h * 16 + 1][lm] = bv.y * scale;
        Bs[lk4 + h * 16 + 2][lm] = bv.z * scale;
        Bs[lk4 + h * 16 + 3][lm] = bv.w * scale;
      }
      __syncthreads();
#pragma unroll
      for (int kk = 0; kk < 32; ++kk) {
        float4 a = *(const float4*)&As[kk][ty * 4];
        float4 b = *(const float4*)&Bs[kk][tx * 4];
        fma16(a, b, acc);
      }
      __syncthreads();
    }
  }
  // ---- gate epilogue ----
  {
    // FIX (R5): load ALL 64 columns of w_back tile. Previous code wrote only
    // lk4 in {0,4,8,12} -> cols [0,16); cols [16,64) were stale LDS garbage,
    // corrupting the gate (absmax err 15.46).
#pragma unroll
    for (int h = 0; h < 4; ++h)
      *(float4*)&Wb[lm][lk4 + h * 16] =
          *(const float4*)&w_back[(long)(i0 + lm) * RCn + (lk4 + h * 16)];
    const int n_ = tid & 63;
    const int rbase = (tid >> 6) * 16;
    const bool nin2 = (j0 + n_) < HWn;
    for (int l = 0; l < 16; ++l) {
      const int rr = rbase + l;
      Ag[n_][rr] = nin2 ? aggb[((long)rr * Tn + t) * HWn + (j0 + n_)] : 0.f;
    }
  }
  __syncthreads();
  float g[4][4] = {};
#pragma unroll
  for (int r4 = 0; r4 < 16; ++r4) {
    float4 wv[4], av[4];
#pragma unroll
    for (int i = 0; i < 4; ++i) wv[i] = *(const float4*)&Wb[ty * 4 + i][r4 * 4];
#pragma unroll
    for (int j = 0; j < 4; ++j) av[j] = *(const float4*)&Ag[tx * 4 + j][r4 * 4];
#pragma unroll
    for (int i = 0; i < 4; ++i)
#pragma unroll
      for (int j = 0; j < 4; ++j)
        g[i][j] += wv[i].x * av[j].x + wv[i].y * av[j].y + wv[i].z * av[j].z +
                   wv[i].w * av[j].w;
  }
  const int n0 = j0 + tx * 4;
  if (n0 < HWn) {
#pragma unroll
    for (int i = 0; i < 4; ++i) {
      const int m = i0 + ty * 4 + i;
      float4 v = make_float4(acc[i][0] * sigm5(g[i][0]), acc[i][1] * sigm5(g[i][1]),
                             acc[i][2] * sigm5(g[i][2]), acc[i][3] * sigm5(g[i][3]));
      *(float4*)&outb[((long)m * Tn + t) * HWn + n0] = v;
    }
  }
}

// Fused 3x depthwise dilated conv3d, weighted sum. One block per (b,r).
__global__ __launch_bounds__(256) void dwconv3(const float* __restrict__ xd,
                                               const float* __restrict__ w1,
                                               const float* __restrict__ bb1,
                                               const float* __restrict__ w2,
                                               const float* __restrict__ bb2,
                                               const float* __restrict__ w3,
                                               const float* __restrict__ bb3,
                                               const float* __restrict__ wts,
                                               float* __restrict__ agg) {
  __shared__ float tile[THWn];
  __shared__ float wl[3][81];
  __shared__ float biasc;
  const int bid = blockIdx.x;  // b*64 + r
  const int r = bid & 63;
  const float* src = xd + (long)bid * THWn;
  for (int i = threadIdx.x; i < THWn; i += 256) tile[i] = src[i];
  if (threadIdx.x < 243) {
    const int i = threadIdx.x / 81, k = threadIdx.x % 81;
    const float* wsrc = (i == 0) ? w1 : (i == 1) ? w2 : w3;
    wl[i][k] = wsrc[r * 81 + k] * wts[i];
  }
  if (threadIdx.x == 0)
    biasc = bb1[r] * wts[0] + bb2[r] * wts[1] + bb3[r] * wts[2];
  __syncthreads();
  for (int idx = threadIdx.x; idx < THWn; idx += 256) {
    const int t = idx / HWn;
    const int rem = idx - t * HWn;
    const int h = rem / Wn;
    const int w = rem - h * Wn;
    float acc = biasc;
#pragma unroll
    for (int d = 0; d < 3; ++d) {
      const int dil = d + 1;
#pragma unroll
      for (int kt = 0; kt < 9; ++kt) {
        const int tt = t + kt - 4;
        if (tt < 0 || tt >= Tn) continue;
#pragma unroll
        for (int kh = 0; kh < 3; ++kh) {
          const int hh = h + (kh - 1) * dil;
          if ((unsigned)hh >= (unsigned)Hn) continue;
#pragma unroll
          for (int kw = 0; kw < 3; ++kw) {
            const int ww = w + (kw - 1) * dil;
            if ((unsigned)ww >= (unsigned)Wn) continue;
            acc = fmaf(tile[(tt * Hn + hh) * Wn + ww], wl[d][kt * 9 + kh * 3 + kw], acc);
          }
        }
      }
    }
    agg[(long)bid * THWn + idx] = acc;
  }
}

extern "C" void kernel_launch(void* const* d_in, const int* in_sizes, int n_in,
                              void* d_out, int out_size, void* d_ws, size_t ws_size,
                              hipStream_t stream) {
  (void)in_sizes; (void)n_in; (void)out_size; (void)ws_size;
  const float* x       = (const float*)d_in[0];
  const float* w_down  = (const float*)d_in[1];
  const float* w_down2 = (const float*)d_in[2];
  const float* w_sa1   = (const float*)d_in[3];
  const float* b_sa1   = (const float*)d_in[4];
  const float* w_sa2   = (const float*)d_in[5];
  const float* b_sa2   = (const float*)d_in[6];
  const float* w_sa3   = (const float*)d_in[7];
  const float* b_sa3   = (const float*)d_in[8];
  const float* w_back  = (const float*)d_in[9];
  const float* wts     = (const float*)d_in[10];
  const float* w2      = (const float*)d_in[11];
  float* out = (float*)d_out;
  float* ws = (float*)d_ws;

  // workspace layout (floats):
  float* xd  = ws;                        // 4*64*12544        = 3,211,264
  float* agg = ws + 3211264;              // 3,211,264
  float* x2  = ws + 6422528;              // 1024*12544        = 12,845,056
  float* Gn  = ws + 19267584;             // TC*784*784        = 2,458,624
  float* Gp  = ws + 21726208;             // 2,458,624  (total 24,184,832 f = 96.7 MB)

  dim3 blk(256);
  // xd = w_down @ x  (all b in one launch)
  gemm_nn<<<dim3(THWn / 64, 1, Bn), blk, 0, stream>>>(
      w_down, x, xd, RCn, THWn, Cn, (long)Cn * THWn, (long)RCn * THWn);
  // agg = weighted sum of 3 depthwise convs
  dwconv3<<<dim3(Bn * RCn), blk, 0, stream>>>(xd, w_sa1, b_sa1, w_sa2, b_sa2,
                                              w_sa3, b_sa3, wts, agg);
  for (int b = 0; b < Bn; ++b) {
    const float* xb = x + (long)b * Cn * THWn;
    // x2_b = w_down2 @ x[b]
    gemm_nn<<<dim3(THWn / 64, Cn / 64, 1), blk, 0, stream>>>(
        w_down2, xb, x2, Cn, THWn, Cn, 0, 0);
    for (int t0 = 0; t0 < Tn; t0 += TC) {
      // Gn/Gp = sigmoid(X^T X2_shift) - 0.5 for t in [t0, t0+TC)
      aff_tn<<<dim3(13, 13, 2 * TC), blk, 0, stream>>>(xb, x2, Gn, Gp, t0);
      // out[b,t] = (X2n Gn^T w20 + X2p Gp^T w21) * (sigmoid(w_back agg[b]) - 0.5)
      feat_nt<<<dim3(13, Cn / 64, TC), blk, 0, stream>>>(
          x2, Gn, Gp, agg + (long)b * RCn * THWn, w_back, w2,
          out + (long)b * Cn * THWn, t0);
    }
  }
}

// Round 7
// 2805.881 us; speedup vs baseline: 4.4760x; 4.4760x over previous
//
#include <hip/hip_runtime.h>
#include <math.h>

#define Bn 4
#define Cn 1024
#define RCn 64
#define Tn 16
#define Hn 28
#define Wn 28
#define HWn 784
#define THWn 12544
#define KP 800  // sd-dim padded for G tiles

typedef __attribute__((ext_vector_type(8))) short short8v;
typedef __attribute__((ext_vector_type(4))) float f32x4;

__device__ __forceinline__ float sigm5(float x) {
  return 1.0f / (1.0f + __expf(-x)) - 0.5f;
}
__device__ __forceinline__ unsigned short f2bf(float f) {  // RNE fp32->bf16
  unsigned u = __float_as_uint(f);
  u += 0x7FFFu + ((u >> 16) & 1u);
  return (unsigned short)(u >> 16);
}
__device__ __forceinline__ float bf2f(unsigned short h) {
  return __uint_as_float(((unsigned)h) << 16);
}

// ---- MFMA tile machinery: 128x128 block, 4 waves (2x2 of 64x64), BK=32 ----
// LDS tiles are [row][k] bf16, row stride 40 (80B: 2-way bank alias = free).
// A rows = output rows m; B rows = output cols n; k contiguous.

__device__ __forceinline__ void stage_bf(short (*L)[40], const unsigned short* src,
                                         long rstride, int nrows, int nk, int tid) {
  const int row = tid >> 1, base = (tid & 1) * 16;
  const unsigned short* p = src + (long)row * rstride + base;
#pragma unroll
  for (int i = 0; i < 4; ++i) {
    const int ks = base + i * 4;
    ushort4 v = make_ushort4(0, 0, 0, 0);
    if (row < nrows && ks < nk) v = *(const ushort4*)(p + i * 4);
    *(ushort4*)&L[row][ks] = v;
  }
}

__device__ __forceinline__ void stage_bf_scale(short (*L)[40], const unsigned short* src,
                                               long rstride, int nrows, float sc, int tid) {
  const int row = tid >> 1, base = (tid & 1) * 16;
  const unsigned short* p = src + (long)row * rstride + base;
#pragma unroll
  for (int i = 0; i < 4; ++i) {
    const int ks = base + i * 4;
    ushort4 v = make_ushort4(0, 0, 0, 0);
    if (row < nrows) {
      ushort4 r = *(const ushort4*)(p + i * 4);
      v.x = f2bf(bf2f(r.x) * sc); v.y = f2bf(bf2f(r.y) * sc);
      v.z = f2bf(bf2f(r.z) * sc); v.w = f2bf(bf2f(r.w) * sc);
    }
    *(ushort4*)&L[row][ks] = v;
  }
}

__device__ __forceinline__ void stage_f32(short (*L)[40], const float* src,
                                          long rstride, int nrows, int tid) {
  const int row = tid >> 1, base = (tid & 1) * 16;
  const float* p = src + (long)row * rstride + base;
#pragma unroll
  for (int i = 0; i < 4; ++i) {
    ushort4 v = make_ushort4(0, 0, 0, 0);
    if (row < nrows) {
      float4 f = *(const float4*)(p + i * 4);
      v.x = f2bf(f.x); v.y = f2bf(f.y); v.z = f2bf(f.z); v.w = f2bf(f.w);
    }
    *(ushort4*)&L[row][base + i * 4] = v;
  }
}

// A-frag: lane holds row (wr*64+f*16+lane&15), k = (lane>>4)*8 + [0..8)
// B-frag: lane holds col (wc*64+f*16+lane&15), same k slice.
__device__ __forceinline__ void mma16(short (*LA)[40], short (*LB)[40],
                                      f32x4 (&acc)[4][4], int wr, int wc, int l15, int klo) {
  short8v a[4], b[4];
#pragma unroll
  for (int f = 0; f < 4; ++f) {
    a[f] = *(const short8v*)&LA[wr * 64 + f * 16 + l15][klo * 8];
    b[f] = *(const short8v*)&LB[wc * 64 + f * 16 + l15][klo * 8];
  }
#pragma unroll
  for (int i = 0; i < 4; ++i)
#pragma unroll
    for (int j = 0; j < 4; ++j)
      acc[i][j] = __builtin_amdgcn_mfma_f32_16x16x32_bf16(a[i], b[j], acc[i][j], 0, 0, 0);
}

// ---- transpose+convert: X_b fp32 [c][thw] -> XT bf16 [thw][c] ----
__global__ __launch_bounds__(256, 2) void transpose_cvt(const float* __restrict__ Xb,
                                                        unsigned short* __restrict__ XT) {
  __shared__ float T[64][68];
  const int c0 = blockIdx.y * 64, p0 = blockIdx.x * 64;
  const int tid = threadIdx.x;
  const int i = tid >> 4, j4 = (tid & 15) * 4;
#pragma unroll
  for (int pass = 0; pass < 4; ++pass) {
    const int ci = i + pass * 16;
    float4 v = *(const float4*)&Xb[(long)(c0 + ci) * THWn + p0 + j4];
    *(float4*)&T[ci][j4] = v;
  }
  __syncthreads();
  const int jj = tid >> 2, cs = (tid & 3) * 16;
#pragma unroll
  for (int q = 0; q < 4; ++q) {
    ushort4 o;
    o.x = f2bf(T[cs + q * 4 + 0][jj]);
    o.y = f2bf(T[cs + q * 4 + 1][jj]);
    o.z = f2bf(T[cs + q * 4 + 2][jj]);
    o.w = f2bf(T[cs + q * 4 + 3][jj]);
    *(ushort4*)&XT[(long)(p0 + jj) * Cn + c0 + cs + q * 4] = o;
  }
}

// ---- x2^T GEMM: x2T[m=thw][o] = XT[m][c] * w_down2[o][c]; also emits x2b[o][thw] ----
__global__ __launch_bounds__(256, 2) void gemm_x2t(const unsigned short* __restrict__ XT,
                                                   const float* __restrict__ Wd2,
                                                   unsigned short* __restrict__ x2T,
                                                   unsigned short* __restrict__ x2b) {
  __shared__ short LA[128][40], LB[128][40];
  __shared__ short TT[64][136];
  const int tid = threadIdx.x;
  const int wid = tid >> 6, wr = wid >> 1, wc = wid & 1;
  const int l = tid & 63, l15 = l & 15, klo = l >> 4;
  const int i0 = blockIdx.y * 128, n0 = blockIdx.x * 128;  // m=thw tile, n=o tile
  f32x4 acc[4][4];
  f32x4 z4 = {0.f, 0.f, 0.f, 0.f};
#pragma unroll
  for (int i = 0; i < 4; ++i)
#pragma unroll
    for (int j = 0; j < 4; ++j) acc[i][j] = z4;
  for (int k0 = 0; k0 < Cn; k0 += 32) {
    stage_bf(LA, XT + (long)i0 * Cn + k0, Cn, 128, 32, tid);
    stage_f32(LB, Wd2 + (long)n0 * Cn + k0, Cn, 128, tid);
    __syncthreads();
    mma16(LA, LB, acc, wr, wc, l15, klo);
    __syncthreads();
  }
  // x2T store (coalesced along o)
#pragma unroll
  for (int fi = 0; fi < 4; ++fi)
#pragma unroll
    for (int fj = 0; fj < 4; ++fj)
#pragma unroll
      for (int j = 0; j < 4; ++j) {
        const int m = i0 + wr * 64 + fi * 16 + klo * 4 + j;
        const int o = n0 + wc * 64 + fj * 16 + l15;
        x2T[(long)m * Cn + o] = f2bf(acc[fi][fj][j]);
      }
  // x2b store via LDS transpose (two 64-o halves)
  for (int h = 0; h < 2; ++h) {
    __syncthreads();
    if (wc == h) {
#pragma unroll
      for (int fi = 0; fi < 4; ++fi)
#pragma unroll
        for (int fj = 0; fj < 4; ++fj)
#pragma unroll
          for (int j = 0; j < 4; ++j)
            TT[fj * 16 + l15][wr * 64 + fi * 16 + klo * 4 + j] = (short)f2bf(acc[fi][fj][j]);
    }
    __syncthreads();
    const int row = tid >> 2, seg = (tid & 3) * 32;
    ushort4* dst = (ushort4*)(x2b + (long)(n0 + h * 64 + row) * THWn + i0 + seg);
#pragma unroll
    for (int q = 0; q < 8; ++q) dst[q] = *(ushort4*)&TT[row][seg + q * 4];
  }
}

// ---- affinities: G[dt][m=hw][n=sd(pad 800)] = sigm5( XT[t]·x2T[ts]^T ) ----
__global__ __launch_bounds__(256, 2) void aff_mfma(const unsigned short* __restrict__ XT,
                                                   const unsigned short* __restrict__ x2T,
                                                   unsigned short* __restrict__ Gn,
                                                   unsigned short* __restrict__ Gp,
                                                   int t0, int TCH) {
  __shared__ short LA[128][40], LB[128][40];
  const int z = blockIdx.z;
  const int pair = z / TCH, dt = z % TCH;
  const int t = t0 + dt;
  const int ts = pair ? max(t - 1, 0) : min(t + 1, Tn - 1);
  const int tid = threadIdx.x;
  const int wid = tid >> 6, wr = wid >> 1, wc = wid & 1;
  const int l = tid & 63, l15 = l & 15, klo = l >> 4;
  const int i0 = blockIdx.y * 128, n0 = blockIdx.x * 128;
  const unsigned short* A = XT + (long)t * HWn * Cn;
  const unsigned short* B = x2T + (long)ts * HWn * Cn;
  unsigned short* G = (pair ? Gp : Gn) + (long)dt * HWn * KP;
  f32x4 acc[4][4];
  f32x4 z4 = {0.f, 0.f, 0.f, 0.f};
#pragma unroll
  for (int i = 0; i < 4; ++i)
#pragma unroll
    for (int j = 0; j < 4; ++j) acc[i][j] = z4;
  for (int k0 = 0; k0 < Cn; k0 += 32) {
    stage_bf(LA, A + (long)i0 * Cn + k0, Cn, HWn - i0, 32, tid);
    stage_bf(LB, B + (long)n0 * Cn + k0, Cn, HWn - n0, 32, tid);
    __syncthreads();
    mma16(LA, LB, acc, wr, wc, l15, klo);
    __syncthreads();
  }
#pragma unroll
  for (int fi = 0; fi < 4; ++fi)
#pragma unroll
    for (int fj = 0; fj < 4; ++fj)
#pragma unroll
      for (int j = 0; j < 4; ++j) {
        const int m = i0 + wr * 64 + fi * 16 + klo * 4 + j;
        const int n = n0 + wc * 64 + fj * 16 + l15;
        if (m < HWn && n < KP)
          G[(long)m * KP + n] = (n < HWn) ? f2bf(sigm5(acc[fi][fj][j])) : (unsigned short)0;
      }
}

// ---- features+gate: out[c][t][hw] = (sum_pair x2b[c][tt,:]·(sc*G)[hw,:]) * sigm5(w_back·aggT) ----
__global__ __launch_bounds__(256, 2) void feat_mfma(const unsigned short* __restrict__ x2b,
                                                    const unsigned short* __restrict__ Gn,
                                                    const unsigned short* __restrict__ Gp,
                                                    const unsigned short* __restrict__ aggT,
                                                    const float* __restrict__ w_back,
                                                    const float* __restrict__ w2p,
                                                    float* __restrict__ outb, int t0) {
  __shared__ short LA[128][40], LB[128][40];
  const int dt = blockIdx.z;
  const int t = t0 + dt;
  const int tn = min(t + 1, Tn - 1), tp = max(t - 1, 0);
  const int tid = threadIdx.x;
  const int wid = tid >> 6, wr = wid >> 1, wc = wid & 1;
  const int l = tid & 63, l15 = l & 15, klo = l >> 4;
  const int i0 = blockIdx.y * 128, n0 = blockIdx.x * 128;  // c tile, hw tile
  const float s0 = w2p[0], s1 = w2p[1];
  f32x4 acc[4][4], g[4][4];
  f32x4 z4 = {0.f, 0.f, 0.f, 0.f};
#pragma unroll
  for (int i = 0; i < 4; ++i)
#pragma unroll
    for (int j = 0; j < 4; ++j) { acc[i][j] = z4; g[i][j] = z4; }
  for (int pair = 0; pair < 2; ++pair) {
    const int tt = pair ? tp : tn;
    const float sc = pair ? s1 : s0;
    const unsigned short* Asrc = x2b + (long)tt * HWn;  // + c*THWn + k
    const unsigned short* Bsrc = (pair ? Gp : Gn) + (long)dt * HWn * KP;
    for (int k0 = 0; k0 < KP; k0 += 32) {
      stage_bf(LA, Asrc + (long)i0 * THWn + k0, THWn, 128, min(32, HWn - k0), tid);
      stage_bf_scale(LB, Bsrc + (long)n0 * KP + k0, KP, HWn - n0, sc, tid);
      __syncthreads();
      mma16(LA, LB, acc, wr, wc, l15, klo);
      __syncthreads();
    }
  }
  // gate: K=64 over r
  for (int k0 = 0; k0 < RCn; k0 += 32) {
    stage_f32(LA, w_back + (long)i0 * RCn + k0, RCn, 128, tid);
    stage_bf(LB, aggT + ((long)t * HWn + n0) * RCn + k0, RCn, HWn - n0, 32, tid);
    __syncthreads();
    mma16(LA, LB, g, wr, wc, l15, klo);
    __syncthreads();
  }
#pragma unroll
  for (int fi = 0; fi < 4; ++fi)
#pragma unroll
    for (int fj = 0; fj < 4; ++fj)
#pragma unroll
      for (int j = 0; j < 4; ++j) {
        const int c = i0 + wr * 64 + fi * 16 + klo * 4 + j;
        const int hw = n0 + wc * 64 + fj * 16 + l15;
        if (hw < HWn)
          outb[((long)c * Tn + t) * HWn + hw] = acc[fi][fj][j] * sigm5(g[fi][fj][j]);
      }
}

// ---- fp32 helper GEMM (xd projection only), unchanged from R6 ----
__device__ __forceinline__ void fma16f(const float4 a, const float4 b, float (&acc)[4][4]) {
  acc[0][0] = fmaf(a.x, b.x, acc[0][0]); acc[0][1] = fmaf(a.x, b.y, acc[0][1]);
  acc[0][2] = fmaf(a.x, b.z, acc[0][2]); acc[0][3] = fmaf(a.x, b.w, acc[0][3]);
  acc[1][0] = fmaf(a.y, b.x, acc[1][0]); acc[1][1] = fmaf(a.y, b.y, acc[1][1]);
  acc[1][2] = fmaf(a.y, b.z, acc[1][2]); acc[1][3] = fmaf(a.y, b.w, acc[1][3]);
  acc[2][0] = fmaf(a.z, b.x, acc[2][0]); acc[2][1] = fmaf(a.z, b.y, acc[2][1]);
  acc[2][2] = fmaf(a.z, b.z, acc[2][2]); acc[2][3] = fmaf(a.z, b.w, acc[2][3]);
  acc[3][0] = fmaf(a.w, b.x, acc[3][0]); acc[3][1] = fmaf(a.w, b.y, acc[3][1]);
  acc[3][2] = fmaf(a.w, b.z, acc[3][2]); acc[3][3] = fmaf(a.w, b.w, acc[3][3]);
}

__global__ __launch_bounds__(256) void gemm_nn(const float* __restrict__ A,
                                               const float* __restrict__ B,
                                               float* __restrict__ C,
                                               int M, int N, int K, long sB, long sC) {
  __shared__ __align__(16) float As[32][68];
  __shared__ __align__(16) float Bs[32][68];
  const int tid = threadIdx.x;
  const int i0 = blockIdx.y * 64, j0 = blockIdx.x * 64;
  const float* Bp = B + (long)blockIdx.z * sB;
  float* Cp = C + (long)blockIdx.z * sC;
  const int tx = tid & 15, ty = tid >> 4;
  const int lm = tid >> 2, lk = (tid & 3) * 4;
  const int bkk = tid >> 4, bn = (tid & 15) * 4;
  float acc[4][4] = {};
  for (int k0 = 0; k0 < K; k0 += 32) {
#pragma unroll
    for (int h = 0; h < 2; ++h) {
      float4 av = *(const float4*)&A[(long)(i0 + lm) * K + (k0 + lk + h * 16)];
      As[lk + h * 16 + 0][lm] = av.x;
      As[lk + h * 16 + 1][lm] = av.y;
      As[lk + h * 16 + 2][lm] = av.z;
      As[lk + h * 16 + 3][lm] = av.w;
      *(float4*)&Bs[bkk + h * 16][bn] =
          *(const float4*)&Bp[(long)(k0 + bkk + h * 16) * N + (j0 + bn)];
    }
    __syncthreads();
#pragma unroll
    for (int kk = 0; kk < 32; ++kk) {
      float4 a = *(const float4*)&As[kk][ty * 4];
      float4 b = *(const float4*)&Bs[kk][tx * 4];
      fma16f(a, b, acc);
    }
    __syncthreads();
  }
#pragma unroll
  for (int i = 0; i < 4; ++i) {
    float4 v = make_float4(acc[i][0], acc[i][1], acc[i][2], acc[i][3]);
    *(float4*)&Cp[(long)(i0 + ty * 4 + i) * N + (j0 + tx * 4)] = v;
  }
}

// ---- fused depthwise convs -> aggT bf16 [b][thw][r] (transposed for gate GEMM) ----
__global__ __launch_bounds__(1024) void dwconv3(const float* __restrict__ xd,
                                                const float* __restrict__ w1,
                                                const float* __restrict__ bb1,
                                                const float* __restrict__ w2,
                                                const float* __restrict__ bb2,
                                                const float* __restrict__ w3,
                                                const float* __restrict__ bb3,
                                                const float* __restrict__ wts,
                                                unsigned short* __restrict__ aggT) {
  __shared__ float tile[THWn];
  __shared__ float wl[3][81];
  __shared__ float biasc;
  const int bid = blockIdx.x;  // b*64 + r
  const int b = bid >> 6, r = bid & 63;
  const float* src = xd + (long)bid * THWn;
  for (int i = threadIdx.x; i < THWn; i += 1024) tile[i] = src[i];
  if (threadIdx.x < 243) {
    const int i = threadIdx.x / 81, k = threadIdx.x % 81;
    const float* wsrc = (i == 0) ? w1 : (i == 1) ? w2 : w3;
    wl[i][k] = wsrc[r * 81 + k] * wts[i];
  }
  if (threadIdx.x == 0)
    biasc = bb1[r] * wts[0] + bb2[r] * wts[1] + bb3[r] * wts[2];
  __syncthreads();
  for (int idx = threadIdx.x; idx < THWn; idx += 1024) {
    const int t = idx / HWn;
    const int rem = idx - t * HWn;
    const int h = rem / Wn;
    const int w = rem - h * Wn;
    float acc = biasc;
#pragma unroll
    for (int d = 0; d < 3; ++d) {
      const int dil = d + 1;
#pragma unroll
      for (int kt = 0; kt < 9; ++kt) {
        const int tt = t + kt - 4;
        if (tt < 0 || tt >= Tn) continue;
#pragma unroll
        for (int kh = 0; kh < 3; ++kh) {
          const int hh = h + (kh - 1) * dil;
          if ((unsigned)hh >= (unsigned)Hn) continue;
#pragma unroll
          for (int kw = 0; kw < 3; ++kw) {
            const int ww = w + (kw - 1) * dil;
            if ((unsigned)ww >= (unsigned)Wn) continue;
            acc = fmaf(tile[(tt * Hn + hh) * Wn + ww], wl[d][kt * 9 + kh * 3 + kw], acc);
          }
        }
      }
    }
    aggT[((long)b * THWn + idx) * RCn + r] = f2bf(acc);
  }
}

extern "C" void kernel_launch(void* const* d_in, const int* in_sizes, int n_in,
                              void* d_out, int out_size, void* d_ws, size_t ws_size,
                              hipStream_t stream) {
  (void)in_sizes; (void)n_in; (void)out_size;
  const float* x       = (const float*)d_in[0];
  const float* w_down  = (const float*)d_in[1];
  const float* w_down2 = (const float*)d_in[2];
  const float* w_sa1   = (const float*)d_in[3];
  const float* b_sa1   = (const float*)d_in[4];
  const float* w_sa2   = (const float*)d_in[5];
  const float* b_sa2   = (const float*)d_in[6];
  const float* w_sa3   = (const float*)d_in[7];
  const float* b_sa3   = (const float*)d_in[8];
  const float* w_back  = (const float*)d_in[9];
  const float* wts     = (const float*)d_in[10];
  const float* w2      = (const float*)d_in[11];
  float* out = (float*)d_out;
  char* base = (char*)d_ws;

  // workspace (bytes):
  // region0 [0, 25690112): xd fp32 (12.85MB) then XT bf16 (25.69MB) -- stream-ordered alias
  // aggT  bf16 [4][12544][64] : 6,422,528
  // x2T   bf16 [12544][1024]  : 25,690,112 (per b)
  // x2b   bf16 [1024][12544]  : 25,690,112 (per b)
  // Gn,Gp bf16 [TCH][784][800]: TCH*1,254,400 each
  const long R0 = 25690112L;
  float* xd = (float*)base;
  unsigned short* XT   = (unsigned short*)base;
  unsigned short* aggT = (unsigned short*)(base + R0);
  unsigned short* x2T  = (unsigned short*)(base + R0 + 6422528L);
  unsigned short* x2b  = (unsigned short*)(base + R0 + 6422528L + R0);
  unsigned short* Gn   = (unsigned short*)(base + R0 + 6422528L + 2 * R0);
  const int TCH = (ws_size >= (size_t)104000000) ? 8 : 2;  // fallback fits proven 96.7MB
  unsigned short* Gp = Gn + (long)TCH * HWn * KP;

  dim3 blk(256);
  // xd = w_down @ x (fp32, all b)
  gemm_nn<<<dim3(THWn / 64, 1, Bn), blk, 0, stream>>>(
      w_down, x, xd, RCn, THWn, Cn, (long)Cn * THWn, (long)RCn * THWn);
  // aggT = transposed weighted sum of 3 depthwise convs
  dwconv3<<<dim3(Bn * RCn), dim3(1024), 0, stream>>>(xd, w_sa1, b_sa1, w_sa2, b_sa2,
                                                     w_sa3, b_sa3, wts, aggT);
  for (int b = 0; b < Bn; ++b) {
    const float* xb = x + (long)b * Cn * THWn;
    transpose_cvt<<<dim3(196, 16), blk, 0, stream>>>(xb, XT);
    gemm_x2t<<<dim3(8, 98), blk, 0, stream>>>(XT, w_down2, x2T, x2b);
    for (int t0 = 0; t0 < Tn; t0 += TCH) {
      aff_mfma<<<dim3(7, 7, 2 * TCH), blk, 0, stream>>>(XT, x2T, Gn, Gp, t0, TCH);
      feat_mfma<<<dim3(7, 8, TCH), blk, 0, stream>>>(
          x2b, Gn, Gp, aggT + (long)b * THWn * RCn, w_back, w2,
          out + (long)b * Cn * THWn, t0);
    }
  }
}

// Round 11
// 2803.141 us; speedup vs baseline: 4.4804x; 1.0010x over previous
//
#include <hip/hip_runtime.h>
#include <math.h>

#define Bn 4
#define Cn 1024
#define RCn 64
#define Tn 16
#define Hn 28
#define Wn 28
#define HWn 784
#define THWn 12544
#define KP 800  // sd-dim padded for G tiles

typedef __attribute__((ext_vector_type(8))) short short8v;
typedef __attribute__((ext_vector_type(4))) float f32x4;

__device__ __forceinline__ float sigm5(float x) {
  return 1.0f / (1.0f + __expf(-x)) - 0.5f;
}
__device__ __forceinline__ unsigned short f2bf(float f) {  // RNE fp32->bf16
  unsigned u = __float_as_uint(f);
  u += 0x7FFFu + ((u >> 16) & 1u);
  return (unsigned short)(u >> 16);
}
__device__ __forceinline__ float bf2f(unsigned short h) {
  return __uint_as_float(((unsigned)h) << 16);
}

// ---- MFMA tile machinery: 128x128 block, 4 waves (2x2 of 64x64), BK=32 ----
// LDS tiles are [row][k] bf16, row stride 40 (80B: 2-way bank alias = free).

__device__ __forceinline__ void stage_bf(short (*L)[40], const unsigned short* src,
                                         long rstride, int nrows, int nk, int tid) {
  const int row = tid >> 1, base = (tid & 1) * 16;
  const unsigned short* p = src + (long)row * rstride + base;
#pragma unroll
  for (int i = 0; i < 4; ++i) {
    const int ks = base + i * 4;
    ushort4 v = make_ushort4(0, 0, 0, 0);
    if (row < nrows && ks < nk) v = *(const ushort4*)(p + i * 4);
    *(ushort4*)&L[row][ks] = v;
  }
}

__device__ __forceinline__ void stage_bf_scale(short (*L)[40], const unsigned short* src,
                                               long rstride, int nrows, float sc, int tid) {
  const int row = tid >> 1, base = (tid & 1) * 16;
  const unsigned short* p = src + (long)row * rstride + base;
#pragma unroll
  for (int i = 0; i < 4; ++i) {
    const int ks = base + i * 4;
    ushort4 v = make_ushort4(0, 0, 0, 0);
    if (row < nrows) {
      ushort4 r = *(const ushort4*)(p + i * 4);
      v.x = f2bf(bf2f(r.x) * sc); v.y = f2bf(bf2f(r.y) * sc);
      v.z = f2bf(bf2f(r.z) * sc); v.w = f2bf(bf2f(r.w) * sc);
    }
    *(ushort4*)&L[row][ks] = v;
  }
}

__device__ __forceinline__ void stage_f32(short (*L)[40], const float* src,
                                          long rstride, int nrows, int tid) {
  const int row = tid >> 1, base = (tid & 1) * 16;
  const float* p = src + (long)row * rstride + base;
#pragma unroll
  for (int i = 0; i < 4; ++i) {
    ushort4 v = make_ushort4(0, 0, 0, 0);
    if (row < nrows) {
      float4 f = *(const float4*)(p + i * 4);
      v.x = f2bf(f.x); v.y = f2bf(f.y); v.z = f2bf(f.z); v.w = f2bf(f.w);
    }
    *(ushort4*)&L[row][base + i * 4] = v;
  }
}

__device__ __forceinline__ void mma16(short (*LA)[40], short (*LB)[40],
                                      f32x4 (&acc)[4][4], int wr, int wc, int l15, int klo) {
  short8v a[4], b[4];
#pragma unroll
  for (int f = 0; f < 4; ++f) {
    a[f] = *(const short8v*)&LA[wr * 64 + f * 16 + l15][klo * 8];
    b[f] = *(const short8v*)&LB[wc * 64 + f * 16 + l15][klo * 8];
  }
#pragma unroll
  for (int i = 0; i < 4; ++i)
#pragma unroll
    for (int j = 0; j < 4; ++j)
      acc[i][j] = __builtin_amdgcn_mfma_f32_16x16x32_bf16(a[i], b[j], acc[i][j], 0, 0, 0);
}

// ---- transpose+convert: X_b fp32 [c][thw] -> XT bf16 [thw][c] ----
__global__ __launch_bounds__(256, 2) void transpose_cvt(const float* __restrict__ Xb,
                                                        unsigned short* __restrict__ XT) {
  __shared__ float T[64][68];
  const int c0 = blockIdx.y * 64, p0 = blockIdx.x * 64;
  const int tid = threadIdx.x;
  const int i = tid >> 4, j4 = (tid & 15) * 4;
#pragma unroll
  for (int pass = 0; pass < 4; ++pass) {
    const int ci = i + pass * 16;
    float4 v = *(const float4*)&Xb[(long)(c0 + ci) * THWn + p0 + j4];
    *(float4*)&T[ci][j4] = v;
  }
  __syncthreads();
  const int jj = tid >> 2, cs = (tid & 3) * 16;
#pragma unroll
  for (int q = 0; q < 4; ++q) {
    ushort4 o;
    o.x = f2bf(T[cs + q * 4 + 0][jj]);
    o.y = f2bf(T[cs + q * 4 + 1][jj]);
    o.z = f2bf(T[cs + q * 4 + 2][jj]);
    o.w = f2bf(T[cs + q * 4 + 3][jj]);
    *(ushort4*)&XT[(long)(p0 + jj) * Cn + c0 + cs + q * 4] = o;
  }
}

// ---- agg transpose: agg bf16 [b*64+r][thw] -> aggT bf16 [b][thw][64] ----
__global__ __launch_bounds__(256) void transpose_agg(const unsigned short* __restrict__ agg,
                                                     unsigned short* __restrict__ aggT) {
  __shared__ unsigned short T[64][72];
  const int b = blockIdx.y, p0 = blockIdx.x * 64;
  const int tid = threadIdx.x;
  {
    const int r = tid >> 2, cs = (tid & 3) * 16;
    const unsigned short* p = agg + (long)(b * 64 + r) * THWn + p0 + cs;
#pragma unroll
    for (int q = 0; q < 4; ++q) {
      ushort4 v = *(const ushort4*)(p + q * 4);
      *(ushort4*)&T[r][cs + q * 4] = v;
    }
  }
  __syncthreads();
  {
    const int c = tid >> 2, rs = (tid & 3) * 16;
    unsigned short* dst = aggT + ((long)b * THWn + p0 + c) * RCn + rs;
#pragma unroll
    for (int q = 0; q < 4; ++q) {
      ushort4 o;
      o.x = T[rs + q * 4 + 0][c];
      o.y = T[rs + q * 4 + 1][c];
      o.z = T[rs + q * 4 + 2][c];
      o.w = T[rs + q * 4 + 3][c];
      *(ushort4*)(dst + q * 4) = o;
    }
  }
}

// ---- x2^T GEMM: x2T[m=thw][o] = XT[m][c] * w_down2[o][c]; also emits x2b[o][thw] ----
__global__ __launch_bounds__(256, 2) void gemm_x2t(const unsigned short* __restrict__ XT,
                                                   const float* __restrict__ Wd2,
                                                   unsigned short* __restrict__ x2T,
                                                   unsigned short* __restrict__ x2b) {
  __shared__ short LA[128][40], LB[128][40];
  __shared__ short TT[64][136];
  const int tid = threadIdx.x;
  const int wid = tid >> 6, wr = wid >> 1, wc = wid & 1;
  const int l = tid & 63, l15 = l & 15, klo = l >> 4;
  const int i0 = blockIdx.y * 128, n0 = blockIdx.x * 128;
  f32x4 acc[4][4];
  f32x4 z4 = {0.f, 0.f, 0.f, 0.f};
#pragma unroll
  for (int i = 0; i < 4; ++i)
#pragma unroll
    for (int j = 0; j < 4; ++j) acc[i][j] = z4;
  for (int k0 = 0; k0 < Cn; k0 += 32) {
    stage_bf(LA, XT + (long)i0 * Cn + k0, Cn, 128, 32, tid);
    stage_f32(LB, Wd2 + (long)n0 * Cn + k0, Cn, 128, tid);
    __syncthreads();
    mma16(LA, LB, acc, wr, wc, l15, klo);
    __syncthreads();
  }
#pragma unroll
  for (int fi = 0; fi < 4; ++fi)
#pragma unroll
    for (int fj = 0; fj < 4; ++fj)
#pragma unroll
      for (int j = 0; j < 4; ++j) {
        const int m = i0 + wr * 64 + fi * 16 + klo * 4 + j;
        const int o = n0 + wc * 64 + fj * 16 + l15;
        x2T[(long)m * Cn + o] = f2bf(acc[fi][fj][j]);
      }
  for (int h = 0; h < 2; ++h) {
    __syncthreads();
    if (wc == h) {
#pragma unroll
      for (int fi = 0; fi < 4; ++fi)
#pragma unroll
        for (int fj = 0; fj < 4; ++fj)
#pragma unroll
          for (int j = 0; j < 4; ++j)
            TT[fj * 16 + l15][wr * 64 + fi * 16 + klo * 4 + j] = (short)f2bf(acc[fi][fj][j]);
    }
    __syncthreads();
    const int row = tid >> 2, seg = (tid & 3) * 32;
    ushort4* dst = (ushort4*)(x2b + (long)(n0 + h * 64 + row) * THWn + i0 + seg);
#pragma unroll
    for (int q = 0; q < 8; ++q) dst[q] = *(ushort4*)&TT[row][seg + q * 4];
  }
}

// ---- affinities: G[dt][m=hw][n=sd(pad 800)] = sigm5( XT[t]·x2T[ts]^T ) ----
__global__ __launch_bounds__(256, 2) void aff_mfma(const unsigned short* __restrict__ XT,
                                                   const unsigned short* __restrict__ x2T,
                                                   unsigned short* __restrict__ Gn,
                                                   unsigned short* __restrict__ Gp,
                                                   int t0, int TCH) {
  __shared__ short LA[128][40], LB[128][40];
  const int z = blockIdx.z;
  const int pair = z / TCH, dt = z % TCH;
  const int t = t0 + dt;
  const int ts = pair ? max(t - 1, 0) : min(t + 1, Tn - 1);
  const int tid = threadIdx.x;
  const int wid = tid >> 6, wr = wid >> 1, wc = wid & 1;
  const int l = tid & 63, l15 = l & 15, klo = l >> 4;
  const int i0 = blockIdx.y * 128, n0 = blockIdx.x * 128;
  const unsigned short* A = XT + (long)t * HWn * Cn;
  const unsigned short* B = x2T + (long)ts * HWn * Cn;
  unsigned short* G = (pair ? Gp : Gn) + (long)dt * HWn * KP;
  f32x4 acc[4][4];
  f32x4 z4 = {0.f, 0.f, 0.f, 0.f};
#pragma unroll
  for (int i = 0; i < 4; ++i)
#pragma unroll
    for (int j = 0; j < 4; ++j) acc[i][j] = z4;
  for (int k0 = 0; k0 < Cn; k0 += 32) {
    stage_bf(LA, A + (long)i0 * Cn + k0, Cn, HWn - i0, 32, tid);
    stage_bf(LB, B + (long)n0 * Cn + k0, Cn, HWn - n0, 32, tid);
    __syncthreads();
    mma16(LA, LB, acc, wr, wc, l15, klo);
    __syncthreads();
  }
#pragma unroll
  for (int fi = 0; fi < 4; ++fi)
#pragma unroll
    for (int fj = 0; fj < 4; ++fj)
#pragma unroll
      for (int j = 0; j < 4; ++j) {
        const int m = i0 + wr * 64 + fi * 16 + klo * 4 + j;
        const int n = n0 + wc * 64 + fj * 16 + l15;
        if (m < HWn && n < KP)
          G[(long)m * KP + n] = (n < HWn) ? f2bf(sigm5(acc[fi][fj][j])) : (unsigned short)0;
      }
}

// ---- features+gate ----
__global__ __launch_bounds__(256, 2) void feat_mfma(const unsigned short* __restrict__ x2b,
                                                    const unsigned short* __restrict__ Gn,
                                                    const unsigned short* __restrict__ Gp,
                                                    const unsigned short* __restrict__ aggT,
                                                    const float* __restrict__ w_back,
                                                    const float* __restrict__ w2p,
                                                    float* __restrict__ outb, int t0) {
  __shared__ short LA[128][40], LB[128][40];
  const int dt = blockIdx.z;
  const int t = t0 + dt;
  const int tn = min(t + 1, Tn - 1), tp = max(t - 1, 0);
  const int tid = threadIdx.x;
  const int wid = tid >> 6, wr = wid >> 1, wc = wid & 1;
  const int l = tid & 63, l15 = l & 15, klo = l >> 4;
  const int i0 = blockIdx.y * 128, n0 = blockIdx.x * 128;
  const float s0 = w2p[0], s1 = w2p[1];
  f32x4 acc[4][4], g[4][4];
  f32x4 z4 = {0.f, 0.f, 0.f, 0.f};
#pragma unroll
  for (int i = 0; i < 4; ++i)
#pragma unroll
    for (int j = 0; j < 4; ++j) { acc[i][j] = z4; g[i][j] = z4; }
  for (int pair = 0; pair < 2; ++pair) {
    const int tt = pair ? tp : tn;
    const float sc = pair ? s1 : s0;
    const unsigned short* Asrc = x2b + (long)tt * HWn;
    const unsigned short* Bsrc = (pair ? Gp : Gn) + (long)dt * HWn * KP;
    for (int k0 = 0; k0 < KP; k0 += 32) {
      stage_bf(LA, Asrc + (long)i0 * THWn + k0, THWn, 128, min(32, HWn - k0), tid);
      stage_bf_scale(LB, Bsrc + (long)n0 * KP + k0, KP, HWn - n0, sc, tid);
      __syncthreads();
      mma16(LA, LB, acc, wr, wc, l15, klo);
      __syncthreads();
    }
  }
  for (int k0 = 0; k0 < RCn; k0 += 32) {
    stage_f32(LA, w_back + (long)i0 * RCn + k0, RCn, 128, tid);
    stage_bf(LB, aggT + ((long)t * HWn + n0) * RCn + k0, RCn, HWn - n0, 32, tid);
    __syncthreads();
    mma16(LA, LB, g, wr, wc, l15, klo);
    __syncthreads();
  }
#pragma unroll
  for (int fi = 0; fi < 4; ++fi)
#pragma unroll
    for (int fj = 0; fj < 4; ++fj)
#pragma unroll
      for (int j = 0; j < 4; ++j) {
        const int c = i0 + wr * 64 + fi * 16 + klo * 4 + j;
        const int hw = n0 + wc * 64 + fj * 16 + l15;
        if (hw < HWn)
          outb[((long)c * Tn + t) * HWn + hw] = acc[fi][fj][j] * sigm5(g[fi][fj][j]);
      }
}

// ---- fp32 helper GEMM (xd projection only) ----
__device__ __forceinline__ void fma16f(const float4 a, const float4 b, float (&acc)[4][4]) {
  acc[0][0] = fmaf(a.x, b.x, acc[0][0]); acc[0][1] = fmaf(a.x, b.y, acc[0][1]);
  acc[0][2] = fmaf(a.x, b.z, acc[0][2]); acc[0][3] = fmaf(a.x, b.w, acc[0][3]);
  acc[1][0] = fmaf(a.y, b.x, acc[1][0]); acc[1][1] = fmaf(a.y, b.y, acc[1][1]);
  acc[1][2] = fmaf(a.y, b.z, acc[1][2]); acc[1][3] = fmaf(a.y, b.w, acc[1][3]);
  acc[2][0] = fmaf(a.z, b.x, acc[2][0]); acc[2][1] = fmaf(a.z, b.y, acc[2][1]);
  acc[2][2] = fmaf(a.z, b.z, acc[2][2]); acc[2][3] = fmaf(a.z, b.w, acc[2][3]);
  acc[3][0] = fmaf(a.w, b.x, acc[3][0]); acc[3][1] = fmaf(a.w, b.y, acc[3][1]);
  acc[3][2] = fmaf(a.w, b.z, acc[3][2]); acc[3][3] = fmaf(a.w, b.w, acc[3][3]);
}

__global__ __launch_bounds__(256) void gemm_nn(const float* __restrict__ A,
                                               const float* __restrict__ B,
                                               float* __restrict__ C,
                                               int M, int N, int K, long sB, long sC) {
  __shared__ __align__(16) float As[32][68];
  __shared__ __align__(16) float Bs[32][68];
  const int tid = threadIdx.x;
  const int i0 = blockIdx.y * 64, j0 = blockIdx.x * 64;
  const float* Bp = B + (long)blockIdx.z * sB;
  float* Cp = C + (long)blockIdx.z * sC;
  const int tx = tid & 15, ty = tid >> 4;
  const int lm = tid >> 2, lk = (tid & 3) * 4;
  const int bkk = tid >> 4, bn = (tid & 15) * 4;
  float acc[4][4] = {};
  for (int k0 = 0; k0 < K; k0 += 32) {
#pragma unroll
    for (int h = 0; h < 2; ++h) {
      float4 av = *(const float4*)&A[(long)(i0 + lm) * K + (k0 + lk + h * 16)];
      As[lk + h * 16 + 0][lm] = av.x;
      As[lk + h * 16 + 1][lm] = av.y;
      As[lk + h * 16 + 2][lm] = av.z;
      As[lk + h * 16 + 3][lm] = av.w;
      *(float4*)&Bs[bkk + h * 16][bn] =
          *(const float4*)&Bp[(long)(k0 + bkk + h * 16) * N + (j0 + bn)];
    }
    __syncthreads();
#pragma unroll
    for (int kk = 0; kk < 32; ++kk) {
      float4 a = *(const float4*)&As[kk][ty * 4];
      float4 b = *(const float4*)&Bs[kk][tx * 4];
      fma16f(a, b, acc);
    }
    __syncthreads();
  }
#pragma unroll
  for (int i = 0; i < 4; ++i) {
    float4 v = make_float4(acc[i][0], acc[i][1], acc[i][2], acc[i][3]);
    *(float4*)&Cp[(long)(i0 + ty * 4 + i) * N + (j0 + tx * 4)] = v;
  }
}

// ---- fused depthwise convs -> agg bf16 [b*64+r][thw] (COALESCED; R7 fix) ----
__global__ __launch_bounds__(1024) void dwconv3(const float* __restrict__ xd,
                                                const float* __restrict__ w1,
                                                const float* __restrict__ bb1,
                                                const float* __restrict__ w2,
                                                const float* __restrict__ bb2,
                                                const float* __restrict__ w3,
                                                const float* __restrict__ bb3,
                                                const float* __restrict__ wts,
                                                unsigned short* __restrict__ agg) {
  __shared__ float tile[THWn];
  __shared__ float wl[3][81];
  __shared__ float biasc;
  const int bid = blockIdx.x;  // b*64 + r
  const int r = bid & 63;
  const float* src = xd + (long)bid * THWn;
  for (int i = threadIdx.x; i < THWn; i += 1024) tile[i] = src[i];
  if (threadIdx.x < 243) {
    const int i = threadIdx.x / 81, k = threadIdx.x % 81;
    const float* wsrc = (i == 0) ? w1 : (i == 1) ? w2 : w3;
    wl[i][k] = wsrc[r * 81 + k] * wts[i];
  }
  if (threadIdx.x == 0)
    biasc = bb1[r] * wts[0] + bb2[r] * wts[1] + bb3[r] * wts[2];
  __syncthreads();
  for (int idx = threadIdx.x; idx < THWn; idx += 1024) {
    const int t = idx / HWn;
    const int rem = idx - t * HWn;
    const int h = rem / Wn;
    const int w = rem - h * Wn;
    float acc = biasc;
#pragma unroll
    for (int d = 0; d < 3; ++d) {
      const int dil = d + 1;
#pragma unroll
      for (int kt = 0; kt < 9; ++kt) {
        const int tt = t + kt - 4;
        if (tt < 0 || tt >= Tn) continue;
#pragma unroll
        for (int kh = 0; kh < 3; ++kh) {
          const int hh = h + (kh - 1) * dil;
          if ((unsigned)hh >= (unsigned)Hn) continue;
#pragma unroll
          for (int kw = 0; kw < 3; ++kw) {
            const int ww = w + (kw - 1) * dil;
            if ((unsigned)ww >= (unsigned)Wn) continue;
            acc = fmaf(tile[(tt * Hn + hh) * Wn + ww], wl[d][kt * 9 + kh * 3 + kw], acc);
          }
        }
      }
    }
    agg[(long)bid * THWn + idx] = f2bf(acc);  // coalesced 2B stores
  }
}

extern "C" void kernel_launch(void* const* d_in, const int* in_sizes, int n_in,
                              void* d_out, int out_size, void* d_ws, size_t ws_size,
                              hipStream_t stream) {
  (void)in_sizes; (void)n_in; (void)out_size;
  const float* x       = (const float*)d_in[0];
  const float* w_down  = (const float*)d_in[1];
  const float* w_down2 = (const float*)d_in[2];
  const float* w_sa1   = (const float*)d_in[3];
  const float* b_sa1   = (const float*)d_in[4];
  const float* w_sa2   = (const float*)d_in[5];
  const float* b_sa2   = (const float*)d_in[6];
  const float* w_sa3   = (const float*)d_in[7];
  const float* b_sa3   = (const float*)d_in[8];
  const float* w_back  = (const float*)d_in[9];
  const float* wts     = (const float*)d_in[10];
  const float* w2      = (const float*)d_in[11];
  float* out = (float*)d_out;
  char* base = (char*)d_ws;

  // workspace (bytes):
  // region0 [0, 25690112): xd fp32 (12.85MB) @0, agg bf16 (6.42MB) @12845056,
  //   later overwritten per-b by XT bf16 (25.69MB). agg dead before XT write.
  // aggT bf16 [4][12544][64]: 6,422,528
  // x2T  bf16 [12544][1024] : 25,690,112 (per b)
  // x2b  bf16 [1024][12544] : 25,690,112 (per b)
  // Gn,Gp bf16 [TCH][784][800]
  const long R0 = 25690112L;
  float* xd = (float*)base;
  unsigned short* agg  = (unsigned short*)(base + 12845056L);
  unsigned short* XT   = (unsigned short*)base;
  unsigned short* aggT = (unsigned short*)(base + R0);
  unsigned short* x2T  = (unsigned short*)(base + R0 + 6422528L);
  unsigned short* x2b  = (unsigned short*)(base + R0 + 6422528L + R0);
  unsigned short* Gn   = (unsigned short*)(base + R0 + 6422528L + 2 * R0);
  const int TCH = (ws_size >= (size_t)104000000) ? 8 : 2;
  unsigned short* Gp = Gn + (long)TCH * HWn * KP;

  dim3 blk(256);
  // xd = w_down @ x (fp32, all b)
  gemm_nn<<<dim3(THWn / 64, 1, Bn), blk, 0, stream>>>(
      w_down, x, xd, RCn, THWn, Cn, (long)Cn * THWn, (long)RCn * THWn);
  // agg (coalesced) then transpose to aggT
  dwconv3<<<dim3(Bn * RCn), dim3(1024), 0, stream>>>(xd, w_sa1, b_sa1, w_sa2, b_sa2,
                                                     w_sa3, b_sa3, wts, agg);
  transpose_agg<<<dim3(THWn / 64, Bn), blk, 0, stream>>>(agg, aggT);
  for (int b = 0; b < Bn; ++b) {
    const float* xb = x + (long)b * Cn * THWn;
    transpose_cvt<<<dim3(196, 16), blk, 0, stream>>>(xb, XT);
    gemm_x2t<<<dim3(8, 98), blk, 0, stream>>>(XT, w_down2, x2T, x2b);
    for (int t0 = 0; t0 < Tn; t0 += TCH) {
      aff_mfma<<<dim3(7, 7, 2 * TCH), blk, 0, stream>>>(XT, x2T, Gn, Gp, t0, TCH);
      feat_mfma<<<dim3(7, 8, TCH), blk, 0, stream>>>(
          x2b, Gn, Gp, aggT + (long)b * THWn * RCn, w_back, w2,
          out + (long)b * Cn * THWn, t0);
    }
  }
}

// Round 13
// 2585.355 us; speedup vs baseline: 4.8578x; 1.0842x over previous
//
#include <hip/hip_runtime.h>
#include <math.h>

#define Bn 4
#define Cn 1024
#define RCn 64
#define Tn 16
#define Hn 28
#define Wn 28
#define HWn 784
#define THWn 12544
#define KP 800   // sd-dim padded for G tiles
#define DSEG 1792  // THWn / 7 -- dwconv3 output segment per block

typedef __attribute__((ext_vector_type(8))) short short8v;
typedef __attribute__((ext_vector_type(4))) float f32x4;

__device__ __forceinline__ float sigm5(float x) {
  return 1.0f / (1.0f + __expf(-x)) - 0.5f;
}
__device__ __forceinline__ unsigned short f2bf(float f) {  // RNE fp32->bf16
  unsigned u = __float_as_uint(f);
  u += 0x7FFFu + ((u >> 16) & 1u);
  return (unsigned short)(u >> 16);
}
__device__ __forceinline__ float bf2f(unsigned short h) {
  return __uint_as_float(((unsigned)h) << 16);
}

// ---- MFMA tile machinery: 128x128 block, 4 waves (2x2 of 64x64), BK=32 ----
// LDS tiles are [row][k] bf16, row stride 40 (80B: 2-way bank alias = free).

__device__ __forceinline__ void stage_bf(short (*L)[40], const unsigned short* src,
                                         long rstride, int nrows, int nk, int tid) {
  const int row = tid >> 1, base = (tid & 1) * 16;
  const unsigned short* p = src + (long)row * rstride + base;
#pragma unroll
  for (int i = 0; i < 4; ++i) {
    const int ks = base + i * 4;
    ushort4 v = make_ushort4(0, 0, 0, 0);
    if (row < nrows && ks < nk) v = *(const ushort4*)(p + i * 4);
    *(ushort4*)&L[row][ks] = v;
  }
}

__device__ __forceinline__ void stage_bf_scale(short (*L)[40], const unsigned short* src,
                                               long rstride, int nrows, float sc, int tid) {
  const int row = tid >> 1, base = (tid & 1) * 16;
  const unsigned short* p = src + (long)row * rstride + base;
#pragma unroll
  for (int i = 0; i < 4; ++i) {
    const int ks = base + i * 4;
    ushort4 v = make_ushort4(0, 0, 0, 0);
    if (row < nrows) {
      ushort4 r = *(const ushort4*)(p + i * 4);
      v.x = f2bf(bf2f(r.x) * sc); v.y = f2bf(bf2f(r.y) * sc);
      v.z = f2bf(bf2f(r.z) * sc); v.w = f2bf(bf2f(r.w) * sc);
    }
    *(ushort4*)&L[row][ks] = v;
  }
}

__device__ __forceinline__ void stage_f32(short (*L)[40], const float* src,
                                          long rstride, int nrows, int tid) {
  const int row = tid >> 1, base = (tid & 1) * 16;
  const float* p = src + (long)row * rstride + base;
#pragma unroll
  for (int i = 0; i < 4; ++i) {
    ushort4 v = make_ushort4(0, 0, 0, 0);
    if (row < nrows) {
      float4 f = *(const float4*)(p + i * 4);
      v.x = f2bf(f.x); v.y = f2bf(f.y); v.z = f2bf(f.z); v.w = f2bf(f.w);
    }
    *(ushort4*)&L[row][base + i * 4] = v;
  }
}

__device__ __forceinline__ void mma16(short (*LA)[40], short (*LB)[40],
                                      f32x4 (&acc)[4][4], int wr, int wc, int l15, int klo) {
  short8v a[4], b[4];
#pragma unroll
  for (int f = 0; f < 4; ++f) {
    a[f] = *(const short8v*)&LA[wr * 64 + f * 16 + l15][klo * 8];
    b[f] = *(const short8v*)&LB[wc * 64 + f * 16 + l15][klo * 8];
  }
#pragma unroll
  for (int i = 0; i < 4; ++i)
#pragma unroll
    for (int j = 0; j < 4; ++j)
      acc[i][j] = __builtin_amdgcn_mfma_f32_16x16x32_bf16(a[i], b[j], acc[i][j], 0, 0, 0);
}

// ---- transpose+convert: X_b fp32 [c][thw] -> XT bf16 [thw][c] ----
__global__ __launch_bounds__(256, 2) void transpose_cvt(const float* __restrict__ Xb,
                                                        unsigned short* __restrict__ XT) {
  __shared__ float T[64][68];
  const int c0 = blockIdx.y * 64, p0 = blockIdx.x * 64;
  const int tid = threadIdx.x;
  const int i = tid >> 4, j4 = (tid & 15) * 4;
#pragma unroll
  for (int pass = 0; pass < 4; ++pass) {
    const int ci = i + pass * 16;
    float4 v = *(const float4*)&Xb[(long)(c0 + ci) * THWn + p0 + j4];
    *(float4*)&T[ci][j4] = v;
  }
  __syncthreads();
  const int jj = tid >> 2, cs = (tid & 3) * 16;
#pragma unroll
  for (int q = 0; q < 4; ++q) {
    ushort4 o;
    o.x = f2bf(T[cs + q * 4 + 0][jj]);
    o.y = f2bf(T[cs + q * 4 + 1][jj]);
    o.z = f2bf(T[cs + q * 4 + 2][jj]);
    o.w = f2bf(T[cs + q * 4 + 3][jj]);
    *(ushort4*)&XT[(long)(p0 + jj) * Cn + c0 + cs + q * 4] = o;
  }
}

// ---- agg transpose: agg bf16 [b*64+r][thw] -> aggT bf16 [b][thw][64] ----
__global__ __launch_bounds__(256) void transpose_agg(const unsigned short* __restrict__ agg,
                                                     unsigned short* __restrict__ aggT) {
  __shared__ unsigned short T[64][72];
  const int b = blockIdx.y, p0 = blockIdx.x * 64;
  const int tid = threadIdx.x;
  {
    const int r = tid >> 2, cs = (tid & 3) * 16;
    const unsigned short* p = agg + (long)(b * 64 + r) * THWn + p0 + cs;
#pragma unroll
    for (int q = 0; q < 4; ++q) {
      ushort4 v = *(const ushort4*)(p + q * 4);
      *(ushort4*)&T[r][cs + q * 4] = v;
    }
  }
  __syncthreads();
  {
    const int c = tid >> 2, rs = (tid & 3) * 16;
    unsigned short* dst = aggT + ((long)b * THWn + p0 + c) * RCn + rs;
#pragma unroll
    for (int q = 0; q < 4; ++q) {
      ushort4 o;
      o.x = T[rs + q * 4 + 0][c];
      o.y = T[rs + q * 4 + 1][c];
      o.z = T[rs + q * 4 + 2][c];
      o.w = T[rs + q * 4 + 3][c];
      *(ushort4*)(dst + q * 4) = o;
    }
  }
}

// ---- x2^T GEMM: x2T[m=thw][o] = XT[m][c] * w_down2[o][c]; also emits x2b[o][thw] ----
__global__ __launch_bounds__(256, 2) void gemm_x2t(const unsigned short* __restrict__ XT,
                                                   const float* __restrict__ Wd2,
                                                   unsigned short* __restrict__ x2T,
                                                   unsigned short* __restrict__ x2b) {
  __shared__ short LA[128][40], LB[128][40];
  __shared__ short TT[64][136];
  const int tid = threadIdx.x;
  const int wid = tid >> 6, wr = wid >> 1, wc = wid & 1;
  const int l = tid & 63, l15 = l & 15, klo = l >> 4;
  const int i0 = blockIdx.y * 128, n0 = blockIdx.x * 128;
  f32x4 acc[4][4];
  f32x4 z4 = {0.f, 0.f, 0.f, 0.f};
#pragma unroll
  for (int i = 0; i < 4; ++i)
#pragma unroll
    for (int j = 0; j < 4; ++j) acc[i][j] = z4;
  for (int k0 = 0; k0 < Cn; k0 += 32) {
    stage_bf(LA, XT + (long)i0 * Cn + k0, Cn, 128, 32, tid);
    stage_f32(LB, Wd2 + (long)n0 * Cn + k0, Cn, 128, tid);
    __syncthreads();
    mma16(LA, LB, acc, wr, wc, l15, klo);
    __syncthreads();
  }
#pragma unroll
  for (int fi = 0; fi < 4; ++fi)
#pragma unroll
    for (int fj = 0; fj < 4; ++fj)
#pragma unroll
      for (int j = 0; j < 4; ++j) {
        const int m = i0 + wr * 64 + fi * 16 + klo * 4 + j;
        const int o = n0 + wc * 64 + fj * 16 + l15;
        x2T[(long)m * Cn + o] = f2bf(acc[fi][fj][j]);
      }
  for (int h = 0; h < 2; ++h) {
    __syncthreads();
    if (wc == h) {
#pragma unroll
      for (int fi = 0; fi < 4; ++fi)
#pragma unroll
        for (int fj = 0; fj < 4; ++fj)
#pragma unroll
          for (int j = 0; j < 4; ++j)
            TT[fj * 16 + l15][wr * 64 + fi * 16 + klo * 4 + j] = (short)f2bf(acc[fi][fj][j]);
    }
    __syncthreads();
    const int row = tid >> 2, seg = (tid & 3) * 32;
    ushort4* dst = (ushort4*)(x2b + (long)(n0 + h * 64 + row) * THWn + i0 + seg);
#pragma unroll
    for (int q = 0; q < 8; ++q) dst[q] = *(ushort4*)&TT[row][seg + q * 4];
  }
}

// ---- affinities: G[dt][m=hw][n=sd(pad 800)] = sigm5( XT[t]·x2T[ts]^T ) ----
__global__ __launch_bounds__(256, 2) void aff_mfma(const unsigned short* __restrict__ XT,
                                                   const unsigned short* __restrict__ x2T,
                                                   unsigned short* __restrict__ Gn,
                                                   unsigned short* __restrict__ Gp,
                                                   int t0, int TCH) {
  __shared__ short LA[128][40], LB[128][40];
  const int z = blockIdx.z;
  const int pair = z / TCH, dt = z % TCH;
  const int t = t0 + dt;
  const int ts = pair ? max(t - 1, 0) : min(t + 1, Tn - 1);
  const int tid = threadIdx.x;
  const int wid = tid >> 6, wr = wid >> 1, wc = wid & 1;
  const int l = tid & 63, l15 = l & 15, klo = l >> 4;
  const int i0 = blockIdx.y * 128, n0 = blockIdx.x * 128;
  const unsigned short* A = XT + (long)t * HWn * Cn;
  const unsigned short* B = x2T + (long)ts * HWn * Cn;
  unsigned short* G = (pair ? Gp : Gn) + (long)dt * HWn * KP;
  f32x4 acc[4][4];
  f32x4 z4 = {0.f, 0.f, 0.f, 0.f};
#pragma unroll
  for (int i = 0; i < 4; ++i)
#pragma unroll
    for (int j = 0; j < 4; ++j) acc[i][j] = z4;
  for (int k0 = 0; k0 < Cn; k0 += 32) {
    stage_bf(LA, A + (long)i0 * Cn + k0, Cn, HWn - i0, 32, tid);
    stage_bf(LB, B + (long)n0 * Cn + k0, Cn, HWn - n0, 32, tid);
    __syncthreads();
    mma16(LA, LB, acc, wr, wc, l15, klo);
    __syncthreads();
  }
#pragma unroll
  for (int fi = 0; fi < 4; ++fi)
#pragma unroll
    for (int fj = 0; fj < 4; ++fj)
#pragma unroll
      for (int j = 0; j < 4; ++j) {
        const int m = i0 + wr * 64 + fi * 16 + klo * 4 + j;
        const int n = n0 + wc * 64 + fj * 16 + l15;
        if (m < HWn && n < KP)
          G[(long)m * KP + n] = (n < HWn) ? f2bf(sigm5(acc[fi][fj][j])) : (unsigned short)0;
      }
}

// ---- features+gate ----
__global__ __launch_bounds__(256, 2) void feat_mfma(const unsigned short* __restrict__ x2b,
                                                    const unsigned short* __restrict__ Gn,
                                                    const unsigned short* __restrict__ Gp,
                                                    const unsigned short* __restrict__ aggT,
                                                    const float* __restrict__ w_back,
                                                    const float* __restrict__ w2p,
                                                    float* __restrict__ outb, int t0) {
  __shared__ short LA[128][40], LB[128][40];
  const int dt = blockIdx.z;
  const int t = t0 + dt;
  const int tn = min(t + 1, Tn - 1), tp = max(t - 1, 0);
  const int tid = threadIdx.x;
  const int wid = tid >> 6, wr = wid >> 1, wc = wid & 1;
  const int l = tid & 63, l15 = l & 15, klo = l >> 4;
  const int i0 = blockIdx.y * 128, n0 = blockIdx.x * 128;
  const float s0 = w2p[0], s1 = w2p[1];
  f32x4 acc[4][4], g[4][4];
  f32x4 z4 = {0.f, 0.f, 0.f, 0.f};
#pragma unroll
  for (int i = 0; i < 4; ++i)
#pragma unroll
    for (int j = 0; j < 4; ++j) { acc[i][j] = z4; g[i][j] = z4; }
  for (int pair = 0; pair < 2; ++pair) {
    const int tt = pair ? tp : tn;
    const float sc = pair ? s1 : s0;
    const unsigned short* Asrc = x2b + (long)tt * HWn;
    const unsigned short* Bsrc = (pair ? Gp : Gn) + (long)dt * HWn * KP;
    for (int k0 = 0; k0 < KP; k0 += 32) {
      stage_bf(LA, Asrc + (long)i0 * THWn + k0, THWn, 128, min(32, HWn - k0), tid);
      stage_bf_scale(LB, Bsrc + (long)n0 * KP + k0, KP, HWn - n0, sc, tid);
      __syncthreads();
      mma16(LA, LB, acc, wr, wc, l15, klo);
      __syncthreads();
    }
  }
  for (int k0 = 0; k0 < RCn; k0 += 32) {
    stage_f32(LA, w_back + (long)i0 * RCn + k0, RCn, 128, tid);
    stage_bf(LB, aggT + ((long)t * HWn + n0) * RCn + k0, RCn, HWn - n0, 32, tid);
    __syncthreads();
    mma16(LA, LB, g, wr, wc, l15, klo);
    __syncthreads();
  }
#pragma unroll
  for (int fi = 0; fi < 4; ++fi)
#pragma unroll
    for (int fj = 0; fj < 4; ++fj)
#pragma unroll
      for (int j = 0; j < 4; ++j) {
        const int c = i0 + wr * 64 + fi * 16 + klo * 4 + j;
        const int hw = n0 + wc * 64 + fj * 16 + l15;
        if (hw < HWn)
          outb[((long)c * Tn + t) * HWn + hw] = acc[fi][fj][j] * sigm5(g[fi][fj][j]);
      }
}

// ---- fp32 helper GEMM (xd projection only) ----
__device__ __forceinline__ void fma16f(const float4 a, const float4 b, float (&acc)[4][4]) {
  acc[0][0] = fmaf(a.x, b.x, acc[0][0]); acc[0][1] = fmaf(a.x, b.y, acc[0][1]);
  acc[0][2] = fmaf(a.x, b.z, acc[0][2]); acc[0][3] = fmaf(a.x, b.w, acc[0][3]);
  acc[1][0] = fmaf(a.y, b.x, acc[1][0]); acc[1][1] = fmaf(a.y, b.y, acc[1][1]);
  acc[1][2] = fmaf(a.y, b.z, acc[1][2]); acc[1][3] = fmaf(a.y, b.w, acc[1][3]);
  acc[2][0] = fmaf(a.z, b.x, acc[2][0]); acc[2][1] = fmaf(a.z, b.y, acc[2][1]);
  acc[2][2] = fmaf(a.z, b.z, acc[2][2]); acc[2][3] = fmaf(a.z, b.w, acc[2][3]);
  acc[3][0] = fmaf(a.w, b.x, acc[3][0]); acc[3][1] = fmaf(a.w, b.y, acc[3][1]);
  acc[3][2] = fmaf(a.w, b.z, acc[3][2]); acc[3][3] = fmaf(a.w, b.w, acc[3][3]);
}

__global__ __launch_bounds__(256) void gemm_nn(const float* __restrict__ A,
                                               const float* __restrict__ B,
                                               float* __restrict__ C,
                                               int M, int N, int K, long sB, long sC) {
  __shared__ __align__(16) float As[32][68];
  __shared__ __align__(16) float Bs[32][68];
  const int tid = threadIdx.x;
  const int i0 = blockIdx.y * 64, j0 = blockIdx.x * 64;
  const float* Bp = B + (long)blockIdx.z * sB;
  float* Cp = C + (long)blockIdx.z * sC;
  const int tx = tid & 15, ty = tid >> 4;
  const int lm = tid >> 2, lk = (tid & 3) * 4;
  const int bkk = tid >> 4, bn = (tid & 15) * 4;
  float acc[4][4] = {};
  for (int k0 = 0; k0 < K; k0 += 32) {
#pragma unroll
    for (int h = 0; h < 2; ++h) {
      float4 av = *(const float4*)&A[(long)(i0 + lm) * K + (k0 + lk + h * 16)];
      As[lk + h * 16 + 0][lm] = av.x;
      As[lk + h * 16 + 1][lm] = av.y;
      As[lk + h * 16 + 2][lm] = av.z;
      As[lk + h * 16 + 3][lm] = av.w;
      *(float4*)&Bs[bkk + h * 16][bn] =
          *(const float4*)&Bp[(long)(k0 + bkk + h * 16) * N + (j0 + bn)];
    }
    __syncthreads();
#pragma unroll
    for (int kk = 0; kk < 32; ++kk) {
      float4 a = *(const float4*)&As[kk][ty * 4];
      float4 b = *(const float4*)&Bs[kk][tx * 4];
      fma16f(a, b, acc);
    }
    __syncthreads();
  }
#pragma unroll
  for (int i = 0; i < 4; ++i) {
    float4 v = make_float4(acc[i][0], acc[i][1], acc[i][2], acc[i][3]);
    *(float4*)&Cp[(long)(i0 + ty * 4 + i) * N + (j0 + tx * 4)] = v;
  }
}

// ---- fused depthwise convs -> agg bf16 [b*64+r][thw] ----
// R12: back to 256 threads (R7's 1024-thr/launch_bounds(1024) capped VGPR at 64
// -> scratch spills -> 800MB FETCH). grid.y=7 output segments/block (3 blocks/CU
// via 50KB LDS -> 12 waves/CU TLP); 3 accumulators break the 243-FMA dep chain.
__global__ __launch_bounds__(256) void dwconv3(const float* __restrict__ xd,
                                               const float* __restrict__ w1,
                                               const float* __restrict__ bb1,
                                               const float* __restrict__ w2,
                                               const float* __restrict__ bb2,
                                               const float* __restrict__ w3,
                                               const float* __restrict__ bb3,
                                               const float* __restrict__ wts,
                                               unsigned short* __restrict__ agg) {
  __shared__ float tile[THWn];
  __shared__ float wl[3][81];
  __shared__ float biasc;
  const int bid = blockIdx.x;  // b*64 + r
  const int r = bid & 63;
  const float* src = xd + (long)bid * THWn;
  for (int i = threadIdx.x; i < THWn; i += 256) tile[i] = src[i];
  if (threadIdx.x < 243) {
    const int i = threadIdx.x / 81, k = threadIdx.x % 81;
    const float* wsrc = (i == 0) ? w1 : (i == 1) ? w2 : w3;
    wl[i][k] = wsrc[r * 81 + k] * wts[i];
  }
  if (threadIdx.x == 0)
    biasc = bb1[r] * wts[0] + bb2[r] * wts[1] + bb3[r] * wts[2];
  __syncthreads();
  const int i0 = blockIdx.y * DSEG;
#pragma unroll 1
  for (int ii = 0; ii < DSEG; ii += 256) {
    const int idx = i0 + ii + threadIdx.x;
    const int t = idx / HWn;
    const int rem = idx - t * HWn;
    const int h = rem / Wn;
    const int w = rem - h * Wn;
    float a0 = 0.f, a1 = 0.f, a2 = 0.f;  // independent chains per dilation
#pragma unroll
    for (int kt = 0; kt < 9; ++kt) {
      const int tt = t + kt - 4;
      if (tt < 0 || tt >= Tn) continue;
      const int tb = tt * HWn;
#pragma unroll
      for (int kh = 0; kh < 3; ++kh) {
#pragma unroll
        for (int kw = 0; kw < 3; ++kw) {
          const int widx = kt * 9 + kh * 3 + kw;
          {  // d=0, dil=1
            const int hh = h + (kh - 1), ww = w + (kw - 1);
            if ((unsigned)hh < (unsigned)Hn && (unsigned)ww < (unsigned)Wn)
              a0 = fmaf(tile[tb + hh * Wn + ww], wl[0][widx], a0);
          }
          {  // d=1, dil=2
            const int hh = h + (kh - 1) * 2, ww = w + (kw - 1) * 2;
            if ((unsigned)hh < (unsigned)Hn && (unsigned)ww < (unsigned)Wn)
              a1 = fmaf(tile[tb + hh * Wn + ww], wl[1][widx], a1);
          }
          {  // d=2, dil=3
            const int hh = h + (kh - 1) * 3, ww = w + (kw - 1) * 3;
            if ((unsigned)hh < (unsigned)Hn && (unsigned)ww < (unsigned)Wn)
              a2 = fmaf(tile[tb + hh * Wn + ww], wl[2][widx], a2);
          }
        }
      }
    }
    agg[(long)bid * THWn + idx] = f2bf(biasc + a0 + a1 + a2);
  }
}

extern "C" void kernel_launch(void* const* d_in, const int* in_sizes, int n_in,
                              void* d_out, int out_size, void* d_ws, size_t ws_size,
                              hipStream_t stream) {
  (void)in_sizes; (void)n_in; (void)out_size;
  const float* x       = (const float*)d_in[0];
  const float* w_down  = (const float*)d_in[1];
  const float* w_down2 = (const float*)d_in[2];
  const float* w_sa1   = (const float*)d_in[3];
  const float* b_sa1   = (const float*)d_in[4];
  const float* w_sa2   = (const float*)d_in[5];
  const float* b_sa2   = (const float*)d_in[6];
  const float* w_sa3   = (const float*)d_in[7];
  const float* b_sa3   = (const float*)d_in[8];
  const float* w_back  = (const float*)d_in[9];
  const float* wts     = (const float*)d_in[10];
  const float* w2      = (const float*)d_in[11];
  float* out = (float*)d_out;
  char* base = (char*)d_ws;

  // workspace (bytes):
  // region0 [0, 25690112): xd fp32 (12.85MB) @0, agg bf16 (6.42MB) @12845056,
  //   later overwritten per-b by XT bf16 (25.69MB). agg dead before XT write.
  // aggT bf16 [4][12544][64]: 6,422,528
  // x2T  bf16 [12544][1024] : 25,690,112 (per b)
  // x2b  bf16 [1024][12544] : 25,690,112 (per b)
  // Gn,Gp bf16 [TCH][784][800]
  const long R0 = 25690112L;
  float* xd = (float*)base;
  unsigned short* agg  = (unsigned short*)(base + 12845056L);
  unsigned short* XT   = (unsigned short*)base;
  unsigned short* aggT = (unsigned short*)(base + R0);
  unsigned short* x2T  = (unsigned short*)(base + R0 + 6422528L);
  unsigned short* x2b  = (unsigned short*)(base + R0 + 6422528L + R0);
  unsigned short* Gn   = (unsigned short*)(base + R0 + 6422528L + 2 * R0);
  const int TCH = (ws_size >= (size_t)104000000) ? 8 : 2;
  unsigned short* Gp = Gn + (long)TCH * HWn * KP;

  dim3 blk(256);
  // xd = w_down @ x (fp32, all b)
  gemm_nn<<<dim3(THWn / 64, 1, Bn), blk, 0, stream>>>(
      w_down, x, xd, RCn, THWn, Cn, (long)Cn * THWn, (long)RCn * THWn);
  // agg (coalesced) then transpose to aggT
  dwconv3<<<dim3(Bn * RCn, 7), blk, 0, stream>>>(xd, w_sa1, b_sa1, w_sa2, b_sa2,
                                                 w_sa3, b_sa3, wts, agg);
  transpose_agg<<<dim3(THWn / 64, Bn), blk, 0, stream>>>(agg, aggT);
  for (int b = 0; b < Bn; ++b) {
    const float* xb = x + (long)b * Cn * THWn;
    transpose_cvt<<<dim3(196, 16), blk, 0, stream>>>(xb, XT);
    gemm_x2t<<<dim3(8, 98), blk, 0, stream>>>(XT, w_down2, x2T, x2b);
    for (int t0 = 0; t0 < Tn; t0 += TCH) {
      aff_mfma<<<dim3(7, 7, 2 * TCH), blk, 0, stream>>>(XT, x2T, Gn, Gp, t0, TCH);
      feat_mfma<<<dim3(7, 8, TCH), blk, 0, stream>>>(
          x2b, Gn, Gp, aggT + (long)b * THWn * RCn, w_back, w2,
          out + (long)b * Cn * THWn, t0);
    }
  }
}